// Round 9
// baseline (350.772 us; speedup 1.0000x reference)
//
#include <hip/hip_runtime.h>
#include <hip/hip_bf16.h>
#include <hip/hip_cooperative_groups.h>

namespace cg = cooperative_groups;

#define N_NODES 100000
#define N_EDGES 3200000
#define P_PARTS 8
#define PART    12800                 // 8*12800 = 102400 >= N ; 51.2 KB LDS hist
#define NTH     1024
#define N_QUADS (N_EDGES / 4)

// ---------------- workspace layout (bytes) ----------------
#define OFF_BPART 0         // double[512*5] block stats partials (always fully written)
#define OFF_DEG   20544     // float[102400] (zeroed in phase_pack)
#define OFF_ACC   430144    // float[102400]
#define OFF_DINV  839744    // float[100000]
#define OFF_GS    1239744   // float[100000]
#define OFF_SRC32 1639744   // int[N_EDGES] (12.8 MB)
#define OFF_DST32 14439744  // int[N_EDGES] (12.8 MB) -> ends ~27.2 MB

struct Smem {
    float hist[PART];
    float sA[32], sB[32], sC[32], sU[32], sVv[32];
    float sGB, sSCC;
    double sh[5][16];
};

// per-wave int64-vs-int32 detection: high words of first 64 int64 slots
__device__ __forceinline__ bool detect_is64(const void* ei) {
    const int* p = (const int*)ei;
    int lane = threadIdx.x & 63;
    int hi = p[2 * lane + 1];
    unsigned long long m = __ballot(hi != 0);
    return m == 0ull;  // wave-uniform
}

// ---- phase 0: zero degf + pack edges to int32 + per-block BN stats partials ----
__device__ __forceinline__ void phase_pack(Smem& sm, const float* x, const void* ei,
        double* bpart, float* degf, int* src32, int* dst32) {
    bool is64 = detect_is64(ei);
    int nthr = gridDim.x * NTH;
    int tid = blockIdx.x * NTH + threadIdx.x;
    for (int i = tid; i < P_PARTS * PART; i += nthr) degf[i] = 0.f;
    if (is64) {
        const long long* srcp = (const long long*)ei;
        const long long* dstp = srcp + N_EDGES;
        for (int q = tid; q < N_QUADS; q += nthr) {
            longlong2 s01 = ((const longlong2*)srcp)[2 * q];
            longlong2 s23 = ((const longlong2*)srcp)[2 * q + 1];
            longlong2 d01 = ((const longlong2*)dstp)[2 * q];
            longlong2 d23 = ((const longlong2*)dstp)[2 * q + 1];
            ((int4*)src32)[q] = make_int4((int)s01.x, (int)s01.y, (int)s23.x, (int)s23.y);
            ((int4*)dst32)[q] = make_int4((int)d01.x, (int)d01.y, (int)d23.x, (int)d23.y);
        }
    } else {
        const int* srcp = (const int*)ei;
        const int* dstp = srcp + N_EDGES;
        for (int q = tid; q < N_QUADS; q += nthr) {
            ((int4*)src32)[q] = ((const int4*)srcp)[q];
            ((int4*)dst32)[q] = ((const int4*)dstp)[q];
        }
    }
    // BN stats partial for this block (non-atomic, every block writes)
    double a0 = 0, a1 = 0, a2 = 0, a3 = 0, a4 = 0;
    if (tid < N_NODES) {
        float2 v = ((const float2*)x)[tid];
        double x0 = v.x, x1 = v.y;
        a0 = x0; a1 = x1; a2 = x0 * x0; a3 = x1 * x1; a4 = x0 * x1;
    }
    for (int off = 32; off; off >>= 1) {
        a0 += __shfl_down(a0, off);
        a1 += __shfl_down(a1, off);
        a2 += __shfl_down(a2, off);
        a3 += __shfl_down(a3, off);
        a4 += __shfl_down(a4, off);
    }
    int w = threadIdx.x >> 6;
    if ((threadIdx.x & 63) == 0) {
        sm.sh[0][w] = a0; sm.sh[1][w] = a1; sm.sh[2][w] = a2;
        sm.sh[3][w] = a3; sm.sh[4][w] = a4;
    }
    __syncthreads();
    if (threadIdx.x == 0) {
        double t0 = 0, t1 = 0, t2 = 0, t3 = 0, t4 = 0;
        for (int i = 0; i < 16; i++) {
            t0 += sm.sh[0][i]; t1 += sm.sh[1][i]; t2 += sm.sh[2][i];
            t3 += sm.sh[3][i]; t4 += sm.sh[4][i];
        }
        double* bp = bpart + blockIdx.x * 5;
        bp[0] = t0; bp[1] = t1; bp[2] = t2; bp[3] = t3; bp[4] = t4;
    }
    __syncthreads();
}

// ---- phase 1: LDS-privatized degree histogram ----
__device__ __forceinline__ void phase_deg(Smem& sm, const int* dst32, float* degf) {
    int nb = gridDim.x;
    int p = blockIdx.x & 7, slice = blockIdx.x >> 3, base = p * PART;
    int slice_e = N_EDGES / (nb >> 3);
    for (int i = threadIdx.x; i < PART; i += NTH) sm.hist[i] = 0.f;
    __syncthreads();
    int e0 = slice * slice_e, e1 = e0 + slice_e;
    for (int e = e0 + threadIdx.x * 4; e < e1; e += NTH * 4) {
        int4 d4 = *(const int4*)(dst32 + e);
        unsigned l0 = (unsigned)(d4.x - base);
        unsigned l1 = (unsigned)(d4.y - base);
        unsigned l2 = (unsigned)(d4.z - base);
        unsigned l3 = (unsigned)(d4.w - base);
        if (l0 < PART) atomicAdd(&sm.hist[l0], 1.0f);
        if (l1 < PART) atomicAdd(&sm.hist[l1], 1.0f);
        if (l2 < PART) atomicAdd(&sm.hist[l2], 1.0f);
        if (l3 < PART) atomicAdd(&sm.hist[l3], 1.0f);
    }
    __syncthreads();
    for (int i = threadIdx.x; i < PART; i += NTH) {
        float v = sm.hist[i];
        if (v != 0.f) unsafeAtomicAdd(&degf[base + i], v);
    }
}

// ---- phase 2: consts (from partials) + encoder scalar form ----
__device__ __forceinline__ void phase_enc(Smem& sm, const float* x, const double* bpart,
        const float* w1, const float* b1, const float* gamma, const float* beta,
        const float* prelu_a, const float* w2, const float* b2,
        const float* gcn_w, const float* wb, const float* degf,
        float* dinv, float* gs, float* acc) {
    int nb = gridDim.x;
    if (threadIdx.x < 5) {
        double s = 0;
        for (int b = 0; b < nb; b++) s += bpart[b * 5 + threadIdx.x];
        sm.sh[threadIdx.x][0] = s;
    }
    __syncthreads();
    if (threadIdx.x < 32) {
        int c = threadIdx.x;
        double invN = 1.0 / (double)N_NODES;
        double m0 = sm.sh[0][0] * invN, m1 = sm.sh[1][0] * invN;
        double e00 = sm.sh[2][0] * invN, e11 = sm.sh[3][0] * invN, e01 = sm.sh[4][0] * invN;
        double a = w1[2 * c], b = w1[2 * c + 1], t = b1[c];
        double meanH = a * m0 + b * m1 + t;
        double eh2 = a * a * e00 + b * b * e11 + 2.0 * a * b * e01 +
                     2.0 * t * (a * m0 + b * m1) + t * t;
        double var = eh2 - meanH * meanH;
        double inv = 1.0 / sqrt(var + 1e-5);
        float sc = (float)((double)gamma[c] * inv);
        float shift = beta[c] - (float)meanH * sc;
        sm.sA[c] = (float)a * sc;
        sm.sB[c] = (float)b * sc;
        sm.sC[c] = (float)t * sc + shift;
        float vc = 0.f;
        for (int j = 0; j < 32; j++) vc += wb[j] * gcn_w[j * 32 + c];
        sm.sVv[c] = vc;
        float gb = b2[c] * vc;
        for (int off = 16; off; off >>= 1) gb += __shfl_down(gb, off, 32);
        if (c == 0) sm.sGB = gb;
    }
    __syncthreads();
    if (threadIdx.x < 32) {
        float u = 0.f;
        for (int c = 0; c < 32; c++) u += sm.sVv[c] * w2[c * 32 + threadIdx.x];
        sm.sU[threadIdx.x] = u;
    }
    __syncthreads();
    float alpha = prelu_a[0];
    int n = blockIdx.x * NTH + threadIdx.x;
    if (n < N_NODES) {
        float2 xv = ((const float2*)x)[n];
        float g = sm.sGB;
#pragma unroll
        for (int c = 0; c < 32; c++) {
            float hb = sm.sA[c] * xv.x + sm.sB[c] * xv.y + sm.sC[c];
            float pc = hb >= 0.f ? hb : alpha * hb;
            g += pc * sm.sU[c];
        }
        float di = rsqrtf(degf[n] + 1.0f);
        float gg = di * g;
        dinv[n] = di;
        gs[n] = gg;
        acc[n] = gg;  // self-loop term; finalize multiplies by dinv
    }
    __syncthreads();
}

// ---- phase 3: LDS-privatized scatter acc[dst] += gs[src] ----
__device__ __forceinline__ void phase_scatter(Smem& sm, const int* src32, const int* dst32,
        const float* gs, float* acc) {
    int nb = gridDim.x;
    int p = blockIdx.x & 7, slice = blockIdx.x >> 3, base = p * PART;
    int slice_e = N_EDGES / (nb >> 3);
    for (int i = threadIdx.x; i < PART; i += NTH) sm.hist[i] = 0.f;
    __syncthreads();
    int e0 = slice * slice_e, e1 = e0 + slice_e;
    for (int e = e0 + threadIdx.x * 4; e < e1; e += NTH * 4) {
        int4 d4 = *(const int4*)(dst32 + e);
        int4 s4 = *(const int4*)(src32 + e);
        unsigned l0 = (unsigned)(d4.x - base);
        unsigned l1 = (unsigned)(d4.y - base);
        unsigned l2 = (unsigned)(d4.z - base);
        unsigned l3 = (unsigned)(d4.w - base);
        if (l0 < PART) atomicAdd(&sm.hist[l0], gs[s4.x]);
        if (l1 < PART) atomicAdd(&sm.hist[l1], gs[s4.y]);
        if (l2 < PART) atomicAdd(&sm.hist[l2], gs[s4.z]);
        if (l3 < PART) atomicAdd(&sm.hist[l3], gs[s4.w]);
    }
    __syncthreads();
    for (int i = threadIdx.x; i < PART; i += NTH) {
        float v = sm.hist[i];
        if (v != 0.f) unsafeAtomicAdd(&acc[base + i], v);
    }
}

// ---- phase 4: finalize ----
__device__ __forceinline__ void phase_fin(Smem& sm, const float* dinv, const float* acc,
        const float* gcn_b, const float* wb, const float* bb, float* out) {
    if (threadIdx.x < 32) {
        float pv = wb[threadIdx.x] * gcn_b[threadIdx.x];
        for (int off = 16; off; off >>= 1) pv += __shfl_down(pv, off, 32);
        if (threadIdx.x == 0) sm.sSCC = pv + bb[0];
    }
    __syncthreads();
    int nthr = gridDim.x * NTH;
    for (int n = blockIdx.x * NTH + threadIdx.x; n < N_NODES; n += nthr)
        out[n] = dinv[n] * acc[n] + sm.sSCC;
}

// ---- cooperative mega-kernel ----
__global__ __launch_bounds__(NTH, 8) void mega_kernel(
        const float* x, const void* ei,
        const float* w1, const float* b1, const float* gamma, const float* beta,
        const float* prelu_a, const float* w2, const float* b2,
        const float* gcn_w, const float* gcn_b, const float* wb, const float* bb,
        double* bpart, float* degf, float* acc, float* dinv, float* gs,
        int* src32, int* dst32, float* out) {
    __shared__ Smem sm;
    cg::grid_group grid = cg::this_grid();
    phase_pack(sm, x, ei, bpart, degf, src32, dst32);
    grid.sync();
    phase_deg(sm, dst32, degf);
    grid.sync();
    phase_enc(sm, x, bpart, w1, b1, gamma, beta, prelu_a, w2, b2, gcn_w, wb,
              degf, dinv, gs, acc);
    grid.sync();
    phase_scatter(sm, src32, dst32, gs, acc);
    grid.sync();
    phase_fin(sm, dinv, acc, gcn_b, wb, bb, out);
}

// ---- non-cooperative fallback wrappers (same phases, 5 dispatches) ----
__global__ __launch_bounds__(NTH, 8) void k_pack(const float* x, const void* ei,
        double* bpart, float* degf, int* src32, int* dst32) {
    __shared__ Smem sm;
    phase_pack(sm, x, ei, bpart, degf, src32, dst32);
}
__global__ __launch_bounds__(NTH, 8) void k_deg(const int* dst32, float* degf) {
    __shared__ Smem sm;
    phase_deg(sm, dst32, degf);
}
__global__ __launch_bounds__(NTH, 8) void k_enc(const float* x, const double* bpart,
        const float* w1, const float* b1, const float* gamma, const float* beta,
        const float* prelu_a, const float* w2, const float* b2,
        const float* gcn_w, const float* wb, const float* degf,
        float* dinv, float* gs, float* acc) {
    __shared__ Smem sm;
    phase_enc(sm, x, bpart, w1, b1, gamma, beta, prelu_a, w2, b2, gcn_w, wb,
              degf, dinv, gs, acc);
}
__global__ __launch_bounds__(NTH, 8) void k_scat(const int* src32, const int* dst32,
        const float* gs, float* acc) {
    __shared__ Smem sm;
    phase_scatter(sm, src32, dst32, gs, acc);
}
__global__ __launch_bounds__(NTH, 8) void k_fin(const float* dinv, const float* acc,
        const float* gcn_b, const float* wb, const float* bb, float* out) {
    __shared__ Smem sm;
    phase_fin(sm, dinv, acc, gcn_b, wb, bb, out);
}

extern "C" void kernel_launch(void* const* d_in, const int* in_sizes, int n_in,
                              void* d_out, int out_size, void* d_ws, size_t ws_size,
                              hipStream_t stream) {
    const float* x       = (const float*)d_in[0];
    const void*  ei      = d_in[1];
    const float* w1      = (const float*)d_in[2];
    const float* b1      = (const float*)d_in[3];
    const float* bn_g    = (const float*)d_in[4];
    const float* bn_b    = (const float*)d_in[5];
    const float* prelu_a = (const float*)d_in[6];
    const float* w2      = (const float*)d_in[7];
    const float* b2      = (const float*)d_in[8];
    const float* gcn_w   = (const float*)d_in[9];
    const float* gcn_b   = (const float*)d_in[10];
    const float* wb      = (const float*)d_in[11];
    const float* bb      = (const float*)d_in[12];
    float* out = (float*)d_out;

    char* base = (char*)d_ws;
    double* bpart = (double*)(base + OFF_BPART);
    float*  degf  = (float*)(base + OFF_DEG);
    float*  acc   = (float*)(base + OFF_ACC);
    float*  dinv  = (float*)(base + OFF_DINV);
    float*  gs    = (float*)(base + OFF_GS);
    int*    src32 = (int*)(base + OFF_SRC32);
    int*    dst32 = (int*)(base + OFF_DST32);

    int occ = 0;
    hipError_t oe = hipOccupancyMaxActiveBlocksPerMultiprocessor(&occ, mega_kernel, NTH, 0);
    int nb = (oe == hipSuccess && occ >= 2) ? 512 : 256;  // P_PARTS*slices, slices=64/32

    void* kargs[] = {
        (void*)&x, (void*)&ei, (void*)&w1, (void*)&b1, (void*)&bn_g, (void*)&bn_b,
        (void*)&prelu_a, (void*)&w2, (void*)&b2, (void*)&gcn_w, (void*)&gcn_b,
        (void*)&wb, (void*)&bb, (void*)&bpart, (void*)&degf, (void*)&acc,
        (void*)&dinv, (void*)&gs, (void*)&src32, (void*)&dst32, (void*)&out };

    hipError_t le = hipLaunchCooperativeKernel(mega_kernel, dim3(nb), dim3(NTH),
                                               kargs, 0, stream);
    if (le != hipSuccess) {
        // fallback: same phases as ordinary kernels (stream-ordered)
        k_pack<<<512, NTH, 0, stream>>>(x, ei, bpart, degf, src32, dst32);
        k_deg<<<512, NTH, 0, stream>>>(dst32, degf);
        k_enc<<<512, NTH, 0, stream>>>(x, bpart, w1, b1, bn_g, bn_b, prelu_a, w2, b2,
                                       gcn_w, wb, degf, dinv, gs, acc);
        k_scat<<<512, NTH, 0, stream>>>(src32, dst32, gs, acc);
        k_fin<<<512, NTH, 0, stream>>>(dinv, acc, gcn_b, wb, bb, out);
    }
}

// Round 10
// 261.927 us; speedup vs baseline: 1.3392x; 1.3392x over previous
//
#include <hip/hip_runtime.h>
#include <hip/hip_bf16.h>

#define N_NODES 100000
#define N_EDGES 3200000
#define N_QUADS (N_EDGES / 4)

// ---- pack ----
#define PACK_BLOCKS 512
#define NTH 1024

// ---- deg hist: dual-u16 counters, P=4 ----
#define DPARTS   4
#define DNODES   32768                  // nodes per partition (4*32768 >= N)
#define DWORDS   16384                  // u32 words (64 KB LDS)
#define DSLICES  128
#define DSLICE_E (N_EDGES / DSLICES)    // 25000 (%8==0, *4%16==0)
#define DBLOCKS  (DPARTS * DSLICES)     // 512

// ---- scatter hist: f32, P=7 ----
#define SPARTS   7
#define SPART    16384                  // 64 KB LDS (7*16384=114688 >= N)
#define SSLICES  64
#define SSLICE_E (N_EDGES / SSLICES)    // 50000 (%8==0, *4%16==0)
#define SBLOCKS  (SPARTS * SSLICES)     // 448

// ---------------- workspace layout (bytes) ----------------
#define OFF_BPART 0         // double[512*5] per-block stats partials (all written)
#define OFF_CONST 20480     // float[136]: A32,B32,C32,U32,GB,SCC
#define OFF_DEG   21056     // float[131072] (zeroed by pack)
#define OFF_ACC   545344    // float[114688]
#define OFF_DINV  1004096   // float[N]
#define OFF_GS    1404096   // float[N]
#define OFF_SRC32 1804096   // int[N_EDGES] (12.8 MB)
#define OFF_DST32 14604096  // int[N_EDGES] (12.8 MB) -> ends ~27.4 MB

// per-wave int64-vs-int32 detection: high words of first 64 int64 slots
__device__ __forceinline__ bool detect_is64(const void* ei) {
    const int* p = (const int*)ei;
    int lane = threadIdx.x & 63;
    int hi = p[2 * lane + 1];
    unsigned long long m = __ballot(hi != 0);
    return m == 0ull;  // wave-uniform
}

// ---- K1: zero degf + pack edges to int32 + per-block BN stats partials ----
__global__ __launch_bounds__(NTH) void pack_kernel(
        const float* __restrict__ x, const void* __restrict__ ei,
        double* __restrict__ bpart, float* __restrict__ degf,
        int* __restrict__ src32, int* __restrict__ dst32) {
    __shared__ double sh[5][16];
    bool is64 = detect_is64(ei);
    int nthr = PACK_BLOCKS * NTH;
    int tid = blockIdx.x * NTH + threadIdx.x;

    for (int i = tid; i < DPARTS * DNODES; i += nthr) degf[i] = 0.f;

    if (is64) {
        const long long* srcp = (const long long*)ei;
        const long long* dstp = srcp + N_EDGES;
        for (int q = tid; q < N_QUADS; q += nthr) {
            longlong2 s01 = ((const longlong2*)srcp)[2 * q];
            longlong2 s23 = ((const longlong2*)srcp)[2 * q + 1];
            longlong2 d01 = ((const longlong2*)dstp)[2 * q];
            longlong2 d23 = ((const longlong2*)dstp)[2 * q + 1];
            ((int4*)src32)[q] = make_int4((int)s01.x, (int)s01.y, (int)s23.x, (int)s23.y);
            ((int4*)dst32)[q] = make_int4((int)d01.x, (int)d01.y, (int)d23.x, (int)d23.y);
        }
    } else {
        const int* srcp = (const int*)ei;
        const int* dstp = srcp + N_EDGES;
        for (int q = tid; q < N_QUADS; q += nthr) {
            ((int4*)src32)[q] = ((const int4*)srcp)[q];
            ((int4*)dst32)[q] = ((const int4*)dstp)[q];
        }
    }

    // BN stats partial (non-atomic; every block writes its slot)
    double a0 = 0, a1 = 0, a2 = 0, a3 = 0, a4 = 0;
    if (tid < N_NODES) {
        float2 v = ((const float2*)x)[tid];
        double x0 = v.x, x1 = v.y;
        a0 = x0; a1 = x1; a2 = x0 * x0; a3 = x1 * x1; a4 = x0 * x1;
    }
    for (int off = 32; off; off >>= 1) {
        a0 += __shfl_down(a0, off);
        a1 += __shfl_down(a1, off);
        a2 += __shfl_down(a2, off);
        a3 += __shfl_down(a3, off);
        a4 += __shfl_down(a4, off);
    }
    int w = threadIdx.x >> 6;
    if ((threadIdx.x & 63) == 0) {
        sh[0][w] = a0; sh[1][w] = a1; sh[2][w] = a2; sh[3][w] = a3; sh[4][w] = a4;
    }
    __syncthreads();
    if (threadIdx.x == 0) {
        double t0 = 0, t1 = 0, t2 = 0, t3 = 0, t4 = 0;
        for (int i = 0; i < 16; i++) {
            t0 += sh[0][i]; t1 += sh[1][i]; t2 += sh[2][i]; t3 += sh[3][i]; t4 += sh[4][i];
        }
        double* bp = bpart + blockIdx.x * 5;
        bp[0] = t0; bp[1] = t1; bp[2] = t2; bp[3] = t3; bp[4] = t4;
    }
}

// ---- K2: degree histogram (dual-u16 LDS words) + consts by block 0 ----
__global__ __launch_bounds__(NTH, 8) void deg_kernel(
        const int* __restrict__ dst32, float* __restrict__ degf,
        const double* __restrict__ bpart,
        const float* __restrict__ w1, const float* __restrict__ b1,
        const float* __restrict__ gamma, const float* __restrict__ beta,
        const float* __restrict__ w2, const float* __restrict__ b2,
        const float* __restrict__ gcn_w, const float* __restrict__ wb,
        const float* __restrict__ gcn_b, const float* __restrict__ bb,
        float* __restrict__ consts) {
    __shared__ unsigned hist[DWORDS];
    __shared__ float sV[32];
    __shared__ double sst[5];
    int p = blockIdx.x & (DPARTS - 1);
    int slice = blockIdx.x >> 2;
    int base = p * DNODES;

    for (int i = threadIdx.x; i < DWORDS; i += NTH) hist[i] = 0u;
    __syncthreads();

    int e0 = slice * DSLICE_E, e1 = e0 + DSLICE_E;
    for (int e = e0 + threadIdx.x * 8; e < e1; e += NTH * 8) {
        int4 d0 = *(const int4*)(dst32 + e);
        int4 d1 = *(const int4*)(dst32 + e + 4);
        unsigned l0 = (unsigned)(d0.x - base);
        unsigned l1 = (unsigned)(d0.y - base);
        unsigned l2 = (unsigned)(d0.z - base);
        unsigned l3 = (unsigned)(d0.w - base);
        unsigned l4 = (unsigned)(d1.x - base);
        unsigned l5 = (unsigned)(d1.y - base);
        unsigned l6 = (unsigned)(d1.z - base);
        unsigned l7 = (unsigned)(d1.w - base);
        if (l0 < DNODES) atomicAdd(&hist[l0 >> 1], (l0 & 1) ? 65536u : 1u);
        if (l1 < DNODES) atomicAdd(&hist[l1 >> 1], (l1 & 1) ? 65536u : 1u);
        if (l2 < DNODES) atomicAdd(&hist[l2 >> 1], (l2 & 1) ? 65536u : 1u);
        if (l3 < DNODES) atomicAdd(&hist[l3 >> 1], (l3 & 1) ? 65536u : 1u);
        if (l4 < DNODES) atomicAdd(&hist[l4 >> 1], (l4 & 1) ? 65536u : 1u);
        if (l5 < DNODES) atomicAdd(&hist[l5 >> 1], (l5 & 1) ? 65536u : 1u);
        if (l6 < DNODES) atomicAdd(&hist[l6 >> 1], (l6 & 1) ? 65536u : 1u);
        if (l7 < DNODES) atomicAdd(&hist[l7 >> 1], (l7 & 1) ? 65536u : 1u);
    }
    __syncthreads();
    for (int i = threadIdx.x; i < DWORDS; i += NTH) {
        unsigned v = hist[i];
        if (v) {
            unsigned c0 = v & 0xFFFFu, c1 = v >> 16;
            if (c0) unsafeAtomicAdd(&degf[base + 2 * i], (float)c0);
            if (c1) unsafeAtomicAdd(&degf[base + 2 * i + 1], (float)c1);
        }
    }

    // ---- block 0: reduce bpart -> encoder/head constants ----
    if (blockIdx.x == 0) {
        int t = threadIdx.x;
        if (t < 5) {
            double s = 0;
            for (int b = 0; b < PACK_BLOCKS; b++) s += bpart[b * 5 + t];
            sst[t] = s;
        }
        __syncthreads();
        if (t < 32) {
            int c = t;
            double invN = 1.0 / (double)N_NODES;
            double m0 = sst[0] * invN, m1 = sst[1] * invN;
            double e00 = sst[2] * invN, e11 = sst[3] * invN, e01 = sst[4] * invN;
            double a = w1[2 * c], b = w1[2 * c + 1], tt = b1[c];
            double meanH = a * m0 + b * m1 + tt;
            double eh2 = a * a * e00 + b * b * e11 + 2.0 * a * b * e01 +
                         2.0 * tt * (a * m0 + b * m1) + tt * tt;
            double var = eh2 - meanH * meanH;
            double inv = 1.0 / sqrt(var + 1e-5);
            float sc = (float)((double)gamma[c] * inv);
            float shift = beta[c] - (float)meanH * sc;
            consts[c]      = (float)a * sc;
            consts[32 + c] = (float)b * sc;
            consts[64 + c] = (float)tt * sc + shift;
            float vc = 0.f;
            for (int j = 0; j < 32; j++) vc += wb[j] * gcn_w[j * 32 + c];
            sV[c] = vc;
        }
        __syncthreads();
        if (t < 32) {
            float u = 0.f;
            for (int c = 0; c < 32; c++) u += sV[c] * w2[c * 32 + t];
            consts[96 + t] = u;
            float gb = b2[t] * sV[t];
            for (int off = 16; off; off >>= 1) gb += __shfl_down(gb, off, 32);
            float pv = wb[t] * gcn_b[t];
            for (int off = 16; off; off >>= 1) pv += __shfl_down(pv, off, 32);
            if (t == 0) {
                consts[128] = gb;            // GB = b2 . v
                consts[129] = pv + bb[0];    // SCC
            }
        }
    }
}

// ---- K3: encoder (scalar): gs[n] = dinv * (GB + sum_c PReLU(Ax0+Bx1+C) U[c]) ----
__global__ void encoder_kernel(const float* __restrict__ x, const float* __restrict__ consts,
                               const float* __restrict__ prelu_a, const float* __restrict__ degf,
                               float* __restrict__ dinv, float* __restrict__ gs,
                               float* __restrict__ acc) {
    __shared__ float sA[32], sB[32], sC[32], sU[32];
    __shared__ float sGB;
    if (threadIdx.x < 32) {
        sA[threadIdx.x] = consts[threadIdx.x];
        sB[threadIdx.x] = consts[32 + threadIdx.x];
        sC[threadIdx.x] = consts[64 + threadIdx.x];
        sU[threadIdx.x] = consts[96 + threadIdx.x];
    }
    if (threadIdx.x == 0) sGB = consts[128];
    __syncthreads();
    float alpha = prelu_a[0];
    int n = blockIdx.x * blockDim.x + threadIdx.x;
    if (n < N_NODES) {
        float2 xv = ((const float2*)x)[n];
        float g = sGB;
#pragma unroll
        for (int c = 0; c < 32; c++) {
            float hb = sA[c] * xv.x + sB[c] * xv.y + sC[c];
            float pc = hb >= 0.f ? hb : alpha * hb;
            g += pc * sU[c];
        }
        float di = rsqrtf(degf[n] + 1.0f);
        float gg = di * g;
        dinv[n] = di;
        gs[n] = gg;
        acc[n] = gg;  // self-loop term; finalize multiplies by dinv
    }
}

// ---- K4: scatter hist acc[dst] += gs[src], 8 edges/thread/iter ----
__global__ __launch_bounds__(NTH, 8) void scatter_kernel(
        const int* __restrict__ src32, const int* __restrict__ dst32,
        const float* __restrict__ gs, float* __restrict__ acc) {
    __shared__ float hist[SPART];
    int p = blockIdx.x % SPARTS;
    int slice = blockIdx.x / SPARTS;
    int base = p * SPART;

    for (int i = threadIdx.x; i < SPART; i += NTH) hist[i] = 0.f;
    __syncthreads();

    int e0 = slice * SSLICE_E, e1 = e0 + SSLICE_E;
    for (int e = e0 + threadIdx.x * 8; e < e1; e += NTH * 8) {
        int4 d0 = *(const int4*)(dst32 + e);
        int4 d1 = *(const int4*)(dst32 + e + 4);
        int4 s0 = *(const int4*)(src32 + e);
        int4 s1 = *(const int4*)(src32 + e + 4);
        unsigned l0 = (unsigned)(d0.x - base);
        unsigned l1 = (unsigned)(d0.y - base);
        unsigned l2 = (unsigned)(d0.z - base);
        unsigned l3 = (unsigned)(d0.w - base);
        unsigned l4 = (unsigned)(d1.x - base);
        unsigned l5 = (unsigned)(d1.y - base);
        unsigned l6 = (unsigned)(d1.z - base);
        unsigned l7 = (unsigned)(d1.w - base);
        if (l0 < SPART) atomicAdd(&hist[l0], gs[s0.x]);
        if (l1 < SPART) atomicAdd(&hist[l1], gs[s0.y]);
        if (l2 < SPART) atomicAdd(&hist[l2], gs[s0.z]);
        if (l3 < SPART) atomicAdd(&hist[l3], gs[s0.w]);
        if (l4 < SPART) atomicAdd(&hist[l4], gs[s1.x]);
        if (l5 < SPART) atomicAdd(&hist[l5], gs[s1.y]);
        if (l6 < SPART) atomicAdd(&hist[l6], gs[s1.z]);
        if (l7 < SPART) atomicAdd(&hist[l7], gs[s1.w]);
    }
    __syncthreads();
    for (int i = threadIdx.x; i < SPART; i += NTH) {
        float v = hist[i];
        if (v != 0.f) unsafeAtomicAdd(&acc[base + i], v);
    }
}

// ---- K5: finalize: out = dinv*acc + SCC ----
__global__ void finalize_kernel(const float* __restrict__ dinv, const float* __restrict__ acc,
                                const float* __restrict__ consts, float* __restrict__ out) {
    float scc = consts[129];
    int n = blockIdx.x * blockDim.x + threadIdx.x;
    if (n < N_NODES) out[n] = dinv[n] * acc[n] + scc;
}

extern "C" void kernel_launch(void* const* d_in, const int* in_sizes, int n_in,
                              void* d_out, int out_size, void* d_ws, size_t ws_size,
                              hipStream_t stream) {
    const float* x       = (const float*)d_in[0];
    const void*  ei      = d_in[1];
    const float* w1      = (const float*)d_in[2];
    const float* b1      = (const float*)d_in[3];
    const float* bn_g    = (const float*)d_in[4];
    const float* bn_b    = (const float*)d_in[5];
    const float* prelu_a = (const float*)d_in[6];
    const float* w2      = (const float*)d_in[7];
    const float* b2      = (const float*)d_in[8];
    const float* gcn_w   = (const float*)d_in[9];
    const float* gcn_b   = (const float*)d_in[10];
    const float* wb      = (const float*)d_in[11];
    const float* bb      = (const float*)d_in[12];
    float* out = (float*)d_out;

    char* base = (char*)d_ws;
    double* bpart  = (double*)(base + OFF_BPART);
    float*  consts = (float*)(base + OFF_CONST);
    float*  degf   = (float*)(base + OFF_DEG);
    float*  acc    = (float*)(base + OFF_ACC);
    float*  dinv   = (float*)(base + OFF_DINV);
    float*  gs     = (float*)(base + OFF_GS);
    int*    src32  = (int*)(base + OFF_SRC32);
    int*    dst32  = (int*)(base + OFF_DST32);

    pack_kernel<<<PACK_BLOCKS, NTH, 0, stream>>>(x, ei, bpart, degf, src32, dst32);
    deg_kernel<<<DBLOCKS, NTH, 0, stream>>>(dst32, degf, bpart,
        w1, b1, bn_g, bn_b, w2, b2, gcn_w, wb, gcn_b, bb, consts);
    encoder_kernel<<<(N_NODES + 255) / 256, 256, 0, stream>>>(
        x, consts, prelu_a, degf, dinv, gs, acc);
    scatter_kernel<<<SBLOCKS, NTH, 0, stream>>>(src32, dst32, gs, acc);
    finalize_kernel<<<(N_NODES + 255) / 256, 256, 0, stream>>>(dinv, acc, consts, out);
}

// Round 11
// 198.515 us; speedup vs baseline: 1.7670x; 1.3194x over previous
//
#include <hip/hip_runtime.h>
#include <hip/hip_bf16.h>

#define N_NODES 100000
#define N_EDGES 3200000
#define N_QUADS (N_EDGES / 4)

#define NTH 1024
#define PACK_BLOCKS 512

// ---- hist kernels (R8-proven config): P=8, 12800 nodes, 51.2 KB LDS ----
#define P_PARTS 8
#define PART    12800                    // 8*12800 = 102400 >= N
#define SLICES  64
#define SLICE_E (N_EDGES / SLICES)       // 50000
#define BLOCKS_H (P_PARTS * SLICES)      // 512

// ---------------- workspace layout (bytes) ----------------
#define OFF_BPART 0         // double[512*5] per-block stats partials (all written)
#define OFF_CONST 20480     // float[136]: A32,B32,C32,U32,GB,SCC
#define OFF_DEG   21056     // float[102400] (zeroed by pack)
#define OFF_ACC   430656    // float[102400]
#define OFF_DINV  840256    // float[N]
#define OFF_GS    1240256   // float[N]
#define OFF_SRC32 1640256   // int[N_EDGES] (12.8 MB)
#define OFF_DST32 14440256  // int[N_EDGES] (12.8 MB) -> ends ~27.2 MB

// per-wave int64-vs-int32 detection: high words of first 64 int64 slots
__device__ __forceinline__ bool detect_is64(const void* ei) {
    const int* p = (const int*)ei;
    int lane = threadIdx.x & 63;
    int hi = p[2 * lane + 1];
    unsigned long long m = __ballot(hi != 0);
    return m == 0ull;  // wave-uniform
}

// ---- K1: zero degf + pack edges to int32 + per-block BN stats partials ----
__global__ __launch_bounds__(NTH) void pack_kernel(
        const float* __restrict__ x, const void* __restrict__ ei,
        double* __restrict__ bpart, float* __restrict__ degf,
        int* __restrict__ src32, int* __restrict__ dst32) {
    __shared__ double sh[5][16];
    bool is64 = detect_is64(ei);
    int nthr = PACK_BLOCKS * NTH;
    int tid = blockIdx.x * NTH + threadIdx.x;

    for (int i = tid; i < P_PARTS * PART; i += nthr) degf[i] = 0.f;

    if (is64) {
        const long long* srcp = (const long long*)ei;
        const long long* dstp = srcp + N_EDGES;
        for (int q = tid; q < N_QUADS; q += nthr) {
            longlong2 s01 = ((const longlong2*)srcp)[2 * q];
            longlong2 s23 = ((const longlong2*)srcp)[2 * q + 1];
            longlong2 d01 = ((const longlong2*)dstp)[2 * q];
            longlong2 d23 = ((const longlong2*)dstp)[2 * q + 1];
            ((int4*)src32)[q] = make_int4((int)s01.x, (int)s01.y, (int)s23.x, (int)s23.y);
            ((int4*)dst32)[q] = make_int4((int)d01.x, (int)d01.y, (int)d23.x, (int)d23.y);
        }
    } else {
        const int* srcp = (const int*)ei;
        const int* dstp = srcp + N_EDGES;
        for (int q = tid; q < N_QUADS; q += nthr) {
            ((int4*)src32)[q] = ((const int4*)srcp)[q];
            ((int4*)dst32)[q] = ((const int4*)dstp)[q];
        }
    }

    // BN stats partial (non-atomic; every block writes its slot)
    double a0 = 0, a1 = 0, a2 = 0, a3 = 0, a4 = 0;
    if (tid < N_NODES) {
        float2 v = ((const float2*)x)[tid];
        double x0 = v.x, x1 = v.y;
        a0 = x0; a1 = x1; a2 = x0 * x0; a3 = x1 * x1; a4 = x0 * x1;
    }
    for (int off = 32; off; off >>= 1) {
        a0 += __shfl_down(a0, off);
        a1 += __shfl_down(a1, off);
        a2 += __shfl_down(a2, off);
        a3 += __shfl_down(a3, off);
        a4 += __shfl_down(a4, off);
    }
    int w = threadIdx.x >> 6;
    if ((threadIdx.x & 63) == 0) {
        sh[0][w] = a0; sh[1][w] = a1; sh[2][w] = a2; sh[3][w] = a3; sh[4][w] = a4;
    }
    __syncthreads();
    if (threadIdx.x == 0) {
        double t0 = 0, t1 = 0, t2 = 0, t3 = 0, t4 = 0;
        for (int i = 0; i < 16; i++) {
            t0 += sh[0][i]; t1 += sh[1][i]; t2 += sh[2][i]; t3 += sh[3][i]; t4 += sh[4][i];
        }
        double* bp = bpart + blockIdx.x * 5;
        bp[0] = t0; bp[1] = t1; bp[2] = t2; bp[3] = t3; bp[4] = t4;
    }
}

// ---- K2: degree histogram (R8 config) + consts computed by block 0 ----
__global__ __launch_bounds__(NTH, 8) void deg_kernel(
        const int* __restrict__ dst32, float* __restrict__ degf,
        const double* __restrict__ bpart,
        const float* __restrict__ w1, const float* __restrict__ b1,
        const float* __restrict__ gamma, const float* __restrict__ beta,
        const float* __restrict__ w2, const float* __restrict__ b2,
        const float* __restrict__ gcn_w, const float* __restrict__ wb,
        const float* __restrict__ gcn_b, const float* __restrict__ bb,
        float* __restrict__ consts) {
    __shared__ float hist[PART];
    __shared__ float sV[32];
    __shared__ double sst[5];
    int p = blockIdx.x & (P_PARTS - 1);
    int slice = blockIdx.x >> 3;
    int base = p * PART;

    for (int i = threadIdx.x; i < PART; i += NTH) hist[i] = 0.f;
    __syncthreads();

    int e0 = slice * SLICE_E, e1 = e0 + SLICE_E;
    for (int e = e0 + threadIdx.x * 4; e < e1; e += NTH * 4) {
        int4 d4 = *(const int4*)(dst32 + e);
        unsigned l0 = (unsigned)(d4.x - base);
        unsigned l1 = (unsigned)(d4.y - base);
        unsigned l2 = (unsigned)(d4.z - base);
        unsigned l3 = (unsigned)(d4.w - base);
        if (l0 < PART) atomicAdd(&hist[l0], 1.0f);
        if (l1 < PART) atomicAdd(&hist[l1], 1.0f);
        if (l2 < PART) atomicAdd(&hist[l2], 1.0f);
        if (l3 < PART) atomicAdd(&hist[l3], 1.0f);
    }
    __syncthreads();
    for (int i = threadIdx.x; i < PART; i += NTH) {
        float v = hist[i];
        if (v != 0.f) unsafeAtomicAdd(&degf[base + i], v);
    }

    // ---- block 0: reduce bpart -> encoder/head constants ----
    if (blockIdx.x == 0) {
        int t = threadIdx.x;
        if (t < 5) {
            double s = 0;
            for (int b = 0; b < PACK_BLOCKS; b++) s += bpart[b * 5 + t];
            sst[t] = s;
        }
        __syncthreads();
        if (t < 32) {
            int c = t;
            double invN = 1.0 / (double)N_NODES;
            double m0 = sst[0] * invN, m1 = sst[1] * invN;
            double e00 = sst[2] * invN, e11 = sst[3] * invN, e01 = sst[4] * invN;
            double a = w1[2 * c], b = w1[2 * c + 1], tt = b1[c];
            double meanH = a * m0 + b * m1 + tt;
            double eh2 = a * a * e00 + b * b * e11 + 2.0 * a * b * e01 +
                         2.0 * tt * (a * m0 + b * m1) + tt * tt;
            double var = eh2 - meanH * meanH;
            double inv = 1.0 / sqrt(var + 1e-5);
            float sc = (float)((double)gamma[c] * inv);
            float shift = beta[c] - (float)meanH * sc;
            consts[c]      = (float)a * sc;
            consts[32 + c] = (float)b * sc;
            consts[64 + c] = (float)tt * sc + shift;
            float vc = 0.f;
            for (int j = 0; j < 32; j++) vc += wb[j] * gcn_w[j * 32 + c];
            sV[c] = vc;
        }
        __syncthreads();
        if (t < 32) {
            float u = 0.f;
            for (int c = 0; c < 32; c++) u += sV[c] * w2[c * 32 + t];
            consts[96 + t] = u;
            float gb = b2[t] * sV[t];
            for (int off = 16; off; off >>= 1) gb += __shfl_down(gb, off, 32);
            float pv = wb[t] * gcn_b[t];
            for (int off = 16; off; off >>= 1) pv += __shfl_down(pv, off, 32);
            if (t == 0) {
                consts[128] = gb;            // GB = b2 . v
                consts[129] = pv + bb[0];    // SCC
            }
        }
    }
}

// ---- K3: encoder (scalar): gs[n] = dinv * (GB + sum_c PReLU(Ax0+Bx1+C) U[c]) ----
__global__ __launch_bounds__(NTH) void encoder_kernel(
        const float* __restrict__ x, const float* __restrict__ consts,
        const float* __restrict__ prelu_a, const float* __restrict__ degf,
        float* __restrict__ dinv, float* __restrict__ gs, float* __restrict__ acc) {
    __shared__ float sA[32], sB[32], sC[32], sU[32];
    __shared__ float sGB;
    if (threadIdx.x < 32) {
        sA[threadIdx.x] = consts[threadIdx.x];
        sB[threadIdx.x] = consts[32 + threadIdx.x];
        sC[threadIdx.x] = consts[64 + threadIdx.x];
        sU[threadIdx.x] = consts[96 + threadIdx.x];
    }
    if (threadIdx.x == 0) sGB = consts[128];
    __syncthreads();
    float alpha = prelu_a[0];
    int n = blockIdx.x * NTH + threadIdx.x;
    if (n < N_NODES) {
        float2 xv = ((const float2*)x)[n];
        float g = sGB;
#pragma unroll
        for (int c = 0; c < 32; c++) {
            float hb = sA[c] * xv.x + sB[c] * xv.y + sC[c];
            float pc = hb >= 0.f ? hb : alpha * hb;
            g += pc * sU[c];
        }
        float di = rsqrtf(degf[n] + 1.0f);
        float gg = di * g;
        dinv[n] = di;
        gs[n] = gg;
        acc[n] = gg;  // self-loop term; finalize multiplies by dinv
    }
}

// ---- K4: scatter hist acc[dst] += gs[src] (R8 config, 4-edge unroll) ----
__global__ __launch_bounds__(NTH, 8) void scatter_kernel(
        const int* __restrict__ src32, const int* __restrict__ dst32,
        const float* __restrict__ gs, float* __restrict__ acc) {
    __shared__ float hist[PART];
    int p = blockIdx.x & (P_PARTS - 1);
    int slice = blockIdx.x >> 3;
    int base = p * PART;

    for (int i = threadIdx.x; i < PART; i += NTH) hist[i] = 0.f;
    __syncthreads();

    int e0 = slice * SLICE_E, e1 = e0 + SLICE_E;
    for (int e = e0 + threadIdx.x * 4; e < e1; e += NTH * 4) {
        int4 d4 = *(const int4*)(dst32 + e);
        int4 s4 = *(const int4*)(src32 + e);
        unsigned l0 = (unsigned)(d4.x - base);
        unsigned l1 = (unsigned)(d4.y - base);
        unsigned l2 = (unsigned)(d4.z - base);
        unsigned l3 = (unsigned)(d4.w - base);
        if (l0 < PART) atomicAdd(&hist[l0], gs[s4.x]);
        if (l1 < PART) atomicAdd(&hist[l1], gs[s4.y]);
        if (l2 < PART) atomicAdd(&hist[l2], gs[s4.z]);
        if (l3 < PART) atomicAdd(&hist[l3], gs[s4.w]);
    }
    __syncthreads();
    for (int i = threadIdx.x; i < PART; i += NTH) {
        float v = hist[i];
        if (v != 0.f) unsafeAtomicAdd(&acc[base + i], v);
    }
}

// ---- K5: finalize: out = dinv*acc + SCC ----
__global__ void finalize_kernel(const float* __restrict__ dinv, const float* __restrict__ acc,
                                const float* __restrict__ consts, float* __restrict__ out) {
    float scc = consts[129];
    int n = blockIdx.x * blockDim.x + threadIdx.x;
    if (n < N_NODES) out[n] = dinv[n] * acc[n] + scc;
}

extern "C" void kernel_launch(void* const* d_in, const int* in_sizes, int n_in,
                              void* d_out, int out_size, void* d_ws, size_t ws_size,
                              hipStream_t stream) {
    const float* x       = (const float*)d_in[0];
    const void*  ei      = d_in[1];
    const float* w1      = (const float*)d_in[2];
    const float* b1      = (const float*)d_in[3];
    const float* bn_g    = (const float*)d_in[4];
    const float* bn_b    = (const float*)d_in[5];
    const float* prelu_a = (const float*)d_in[6];
    const float* w2      = (const float*)d_in[7];
    const float* b2      = (const float*)d_in[8];
    const float* gcn_w   = (const float*)d_in[9];
    const float* gcn_b   = (const float*)d_in[10];
    const float* wb      = (const float*)d_in[11];
    const float* bb      = (const float*)d_in[12];
    float* out = (float*)d_out;

    char* base = (char*)d_ws;
    double* bpart  = (double*)(base + OFF_BPART);
    float*  consts = (float*)(base + OFF_CONST);
    float*  degf   = (float*)(base + OFF_DEG);
    float*  acc    = (float*)(base + OFF_ACC);
    float*  dinv   = (float*)(base + OFF_DINV);
    float*  gs     = (float*)(base + OFF_GS);
    int*    src32  = (int*)(base + OFF_SRC32);
    int*    dst32  = (int*)(base + OFF_DST32);

    pack_kernel<<<PACK_BLOCKS, NTH, 0, stream>>>(x, ei, bpart, degf, src32, dst32);
    deg_kernel<<<BLOCKS_H, NTH, 0, stream>>>(dst32, degf, bpart,
        w1, b1, bn_g, bn_b, w2, b2, gcn_w, wb, gcn_b, bb, consts);
    encoder_kernel<<<(N_NODES + NTH - 1) / NTH, NTH, 0, stream>>>(
        x, consts, prelu_a, degf, dinv, gs, acc);
    scatter_kernel<<<BLOCKS_H, NTH, 0, stream>>>(src32, dst32, gs, acc);
    finalize_kernel<<<(N_NODES + 255) / 256, 256, 0, stream>>>(dinv, acc, consts, out);
}